// Round 8
// baseline (2384.965 us; speedup 1.0000x reference)
//
#include <hip/hip_runtime.h>

// out[n,:] = ci[n] * sum_{e: dst[e]==n} sigmoid(<review_feat[e,:], ps_w>) * cj[src[e]] * weight[src[e],:]
//
// ROUND 8 = DIAGNOSTIC ROUND. Three hypotheses in a row were neutral; the
// harness's ~500us poison fills hide every one of our dispatches from the
// top-5 profile, so per-kernel attribution has been guesswork. This round
// internally repeats the two idempotent heavy kernels 8x (compiler-opaque
// barriers between passes) so they EXCEED the fill bar and show up with
// their own dur/hbm_gbps/FETCH columns:
//   kC1_gate   x8  (pure 819MB review_feat stream -> scale[])
//   kD_gather  x8  (CSR gather-reduce from L3-resident weight)
// Repeats write identical values -> output unchanged. kA/kC2 keep x1
// (atomic state not repeat-safe); their cost = total - visible parts.
// Structure otherwise identical to round 7 for 1:1 comparability.

#define KC1_REPEAT 8
#define KD_REPEAT  8

#define TILE_LOG 12
#define TILE (1 << TILE_LOG)   // 4096 elems per scan tile

// ---------------- kZ: zero the degree array ----------------
__global__ __launch_bounds__(256) void kZ_zero(unsigned* __restrict__ p, int n)
{
    const int i = blockIdx.x * 256 + threadIdx.x;
    if (i < n) p[i] = 0u;
}

// ---------------- kA: degree histogram ----------------
__global__ __launch_bounds__(256) void kA_hist(
    const int* __restrict__ dst, unsigned* __restrict__ deg, int E)
{
    const long long stride = (long long)gridDim.x * blockDim.x;
    for (long long e = (long long)blockIdx.x * blockDim.x + threadIdx.x; e < E; e += stride)
        atomicAdd(&deg[dst[e]], 1u);
}

// ---------------- kB1: per-tile exclusive scan (coalesced) ----------------
__global__ __launch_bounds__(1024) void kB1_tile_scan(
    const unsigned* __restrict__ deg, unsigned* __restrict__ offs,
    unsigned* __restrict__ tilesum, int N)
{
    __shared__ unsigned lds[TILE];
    __shared__ unsigned sums[1024];
    const int t = threadIdx.x;
    const int base = blockIdx.x << TILE_LOG;
    #pragma unroll
    for (int i = 0; i < 4; ++i) {
        const int idx = base + t + i * 1024;
        lds[t + i * 1024] = (idx < N) ? deg[idx] : 0u;   // coalesced
    }
    __syncthreads();
    unsigned s = lds[4 * t] + lds[4 * t + 1] + lds[4 * t + 2] + lds[4 * t + 3];
    sums[t] = s;
    __syncthreads();
    for (int off = 1; off < 1024; off <<= 1) {
        const unsigned v = (t >= off) ? sums[t - off] : 0u;
        __syncthreads();
        sums[t] += v;
        __syncthreads();
    }
    unsigned run = sums[t] - s;
    #pragma unroll
    for (int i = 0; i < 4; ++i) {
        const unsigned tmp = lds[4 * t + i];
        lds[4 * t + i] = run;
        run += tmp;
    }
    __syncthreads();
    #pragma unroll
    for (int i = 0; i < 4; ++i) {
        const int idx = base + t + i * 1024;
        if (idx < N) offs[idx] = lds[t + i * 1024];      // coalesced
    }
    if (t == 1023) tilesum[blockIdx.x] = sums[1023];
}

// ---------------- kB2: scan tile totals ----------------
__global__ void kB2_scan_tiles(
    const unsigned* __restrict__ tilesum, unsigned* __restrict__ tileoff,
    unsigned* __restrict__ offs, int ntiles, int N)
{
    if (threadIdx.x == 0 && blockIdx.x == 0) {
        unsigned run = 0;
        for (int b = 0; b < ntiles; ++b) { tileoff[b] = run; run += tilesum[b]; }
        offs[N] = run;   // == E
    }
}

// ---------------- kB3: globalize offsets, emit cursor ----------------
__global__ __launch_bounds__(256) void kB3_add_offs(
    unsigned* __restrict__ offs, unsigned* __restrict__ cursor,
    const unsigned* __restrict__ tileoff, int N)
{
    const long long stride = (long long)gridDim.x * blockDim.x;
    for (long long i = (long long)blockIdx.x * blockDim.x + threadIdx.x; i < N; i += stride) {
        const unsigned o = offs[i] + tileoff[i >> TILE_LOG];
        offs[i] = o;
        cursor[i] = o;
    }
}

// ---------------- kC1: PURE gate stream (x KC1_REPEAT for diagnosis) ----------------
__global__ __launch_bounds__(256) void kC1_gate(
    const float* __restrict__ review_feat,  // [E,64]
    const float* __restrict__ ps_w,         // [64]
    float*       __restrict__ scale,        // [E] out: sigmoid(dot)
    int E)
{
    const int lane  = threadIdx.x & 63;
    const int wib   = threadIdx.x >> 6;
    const int group = lane >> 4;
    const int sub   = lane & 15;
    const float4 pw = *reinterpret_cast<const float4*>(ps_w + sub * 4);

    const long long nwaves = (long long)gridDim.x * 4;
    for (int r = 0; r < KC1_REPEAT; ++r) {
        for (long long w = (long long)blockIdx.x * 4 + wib; w * 16 < E; w += nwaves) {
            const long long ebase = w * 16;
            float4 rv[4];
            #pragma unroll
            for (int u = 0; u < 4; ++u) {
                const long long e = ebase + u * 4 + group;
                rv[u] = (e < E) ? *reinterpret_cast<const float4*>(review_feat + e * 64 + sub * 4)
                                : make_float4(0.f, 0.f, 0.f, 0.f);
            }
            float x[4];
            #pragma unroll
            for (int u = 0; u < 4; ++u) {
                float t = rv[u].x * pw.x + rv[u].y * pw.y + rv[u].z * pw.z + rv[u].w * pw.w;
                t += __shfl_xor(t, 1);
                t += __shfl_xor(t, 2);
                t += __shfl_xor(t, 4);
                t += __shfl_xor(t, 8);
                x[u] = t;
            }
            if (sub == 0) {
                #pragma unroll
                for (int u = 0; u < 4; ++u) {
                    const long long e = ebase + u * 4 + group;
                    if (e < E) scale[e] = 1.f / (1.f + __expf(-x[u]));
                }
            }
        }
        asm volatile("" ::: "memory");   // keep repeat passes distinct
    }
}

// ---------------- kC2: CSR scatter, one thread per edge (x1, stateful) ----------------
__global__ __launch_bounds__(256) void kC2_scatter(
    const int*   __restrict__ src,
    const int*   __restrict__ dst,
    const float* __restrict__ scale,
    const float* __restrict__ cj,
    const float* __restrict__ ci,
    unsigned*    __restrict__ cursor,
    int2*        __restrict__ pairs,
    int E)
{
    const long long e = (long long)blockIdx.x * 256 + threadIdx.x;
    if (e >= E) return;
    const int s = src[e];
    const int d = dst[e];
    const float sc = scale[e] * cj[s] * ci[d];
    const unsigned pos = atomicAdd(&cursor[d], 1u);
    pairs[pos] = make_int2(s, __float_as_int(sc));
}

// ---------------- kD: gather-reduce (x KD_REPEAT for diagnosis) ----------------
__global__ __launch_bounds__(256, 4) void kD_gather(
    const float* __restrict__ weight, const unsigned* __restrict__ offs,
    const int2* __restrict__ pairs, float* __restrict__ out, int N)
{
    const int lane  = threadIdx.x & 63;
    const int wib   = threadIdx.x >> 6;
    const int group = lane >> 4;   // node within wave
    const int sub   = lane & 15;   // float4 chunk of the row

    const long long n = ((long long)blockIdx.x * 4 + wib) * 4 + group;
    const bool valid = (n < N);

    unsigned start = 0, cnt = 0;
    if (valid) { start = offs[n]; cnt = offs[n + 1] - start; }

    for (int r = 0; r < KD_REPEAT; ++r) {
        int2 p = make_int2(0, 0);
        if (sub < cnt) p = pairs[start + sub];

        float4 acc = make_float4(0.f, 0.f, 0.f, 0.f);
        for (unsigned k0 = 0; __any((int)(k0 < cnt)); k0 += 16) {
            int2 pn = make_int2(0, 0);
            const unsigned nk = k0 + 16;
            if (nk + sub < cnt) pn = pairs[start + nk + sub];

            int m = (int)cnt - (int)k0;
            if (m > 16) m = 16;
            #pragma unroll 8
            for (int j = 0; j < m; ++j) {
                const int   s  = __shfl(p.x, (group << 4) + j);
                const float sc = __int_as_float(__shfl(p.y, (group << 4) + j));
                const float4 w = *reinterpret_cast<const float4*>(
                    weight + (long long)s * 64 + sub * 4);
                acc.x += sc * w.x;
                acc.y += sc * w.y;
                acc.z += sc * w.z;
                acc.w += sc * w.w;
            }
            p = pn;
        }
        if (valid)
            *reinterpret_cast<float4*>(out + n * 64 + sub * 4) = acc;
        asm volatile("" ::: "memory");   // keep repeat passes distinct
    }
}

extern "C" void kernel_launch(void* const* d_in, const int* in_sizes, int n_in,
                              void* d_out, int out_size, void* d_ws, size_t ws_size,
                              hipStream_t stream) {
    const float* weight      = (const float*)d_in[0];
    const float* ps_w        = (const float*)d_in[1];
    const float* review_feat = (const float*)d_in[2];
    const float* cj          = (const float*)d_in[3];
    const float* ci          = (const float*)d_in[4];
    const int*   src         = (const int*)d_in[5];
    const int*   dst         = (const int*)d_in[6];
    float*       out         = (float*)d_out;

    const int N = in_sizes[3];
    const int E = in_sizes[5];
    const int ntiles = (N + TILE - 1) / TILE;

    size_t off = 0;
    auto take = [&](size_t bytes) { size_t o = off; off = (off + bytes + 255) & ~(size_t)255; return o; };
    const size_t pairs_o   = take((size_t)E * 8);
    const size_t scale_o   = take((size_t)E * 4);
    const size_t deg_o     = take((size_t)N * 4);
    const size_t offs_o    = take(((size_t)N + 1) * 4);
    const size_t cursor_o  = take((size_t)N * 4);
    const size_t tilesum_o = take((size_t)ntiles * 4);
    const size_t tileoff_o = take((size_t)ntiles * 4);

    char* base = (char*)d_ws;
    int2*     pairs   = (int2*)    (base + pairs_o);
    float*    scale   = (float*)   (base + scale_o);
    unsigned* deg     = (unsigned*)(base + deg_o);
    unsigned* offs    = (unsigned*)(base + offs_o);
    unsigned* cursor  = (unsigned*)(base + cursor_o);
    unsigned* tilesum = (unsigned*)(base + tilesum_o);
    unsigned* tileoff = (unsigned*)(base + tileoff_o);

    kZ_zero<<<(N + 255) / 256, 256, 0, stream>>>(deg, N);
    kA_hist<<<2048, 256, 0, stream>>>(dst, deg, E);
    kB1_tile_scan<<<ntiles, 1024, 0, stream>>>(deg, offs, tilesum, N);
    kB2_scan_tiles<<<1, 64, 0, stream>>>(tilesum, tileoff, offs, ntiles, N);
    kB3_add_offs<<<256, 256, 0, stream>>>(offs, cursor, tileoff, N);
    kC1_gate<<<2048, 256, 0, stream>>>(review_feat, ps_w, scale, E);
    kC2_scatter<<<(E + 255) / 256, 256, 0, stream>>>(src, dst, scale, cj, ci,
                                                     cursor, pairs, E);
    const int blocksD = (N + 15) / 16;   // 16 nodes per block (4 waves x 4 nodes)
    kD_gather<<<blocksD, 256, 0, stream>>>(weight, offs, pairs, out, N);
}

// Round 9
// 584.726 us; speedup vs baseline: 4.0788x; 4.0788x over previous
//
#include <hip/hip_runtime.h>

// out[n,:] = ci[n] * sum_{e: dst[e]==n} sigmoid(<review_feat[e,:], ps_w>) * cj[src[e]] * weight[src[e],:]
//
// Round-8 diagnostic: kC1 ~165us (near stream roofline), kD ~95us (near L3
// gather floor) -> ~300us of the 570 is GLUE (5 small kernels + gaps).
// Round 9 collapses the glue: 8 dispatches -> 5.
//   kZ : zero deg + scan-done counter
//   K2 : gate stream FUSED with deg histogram and cj*ci fold (atomics ride
//        under the BW-bound 819MB stream)
//   K3 : one-dispatch scan: 49 co-resident blocks, publish tile aggregates,
//        device-atomic barrier, per-block prefix, write offs+cursor
//   K4 : scatter (src,scale) pairs via cursor atomics
//   K5 : gather-reduce (unchanged round-6 kD; at its L3-BW floor)

#define SCAN_TILE    2048
#define SCAN_THREADS 512

// ---------------- kZ: zero deg + done ----------------
__global__ __launch_bounds__(256) void kZ_zero(
    unsigned* __restrict__ deg, unsigned* __restrict__ done, int n)
{
    const int i = blockIdx.x * 256 + threadIdx.x;
    if (i < n) deg[i] = 0u;
    if (i == 0) *done = 0u;
}

// ---------------- K2: gate stream + hist + cj*ci fold ----------------
// 16 consecutive edges per wave-iter (4 independent 1KB rv loads in flight).
// sub==0 lanes: gather cj[src], ci[dst], write scale, bump deg[dst].
__global__ __launch_bounds__(256) void k2_gate_hist(
    const float* __restrict__ review_feat,  // [E,64]
    const float* __restrict__ ps_w,         // [64]
    const float* __restrict__ cj,           // [N]
    const float* __restrict__ ci,           // [N]
    const int*   __restrict__ src,          // [E]
    const int*   __restrict__ dst,          // [E]
    float*       __restrict__ scale,        // [E] out: gate*cj*ci
    unsigned*    __restrict__ deg,          // [N] (pre-zeroed)
    int E)
{
    const int lane  = threadIdx.x & 63;
    const int wib   = threadIdx.x >> 6;
    const int group = lane >> 4;
    const int sub   = lane & 15;
    const float4 pw = *reinterpret_cast<const float4*>(ps_w + sub * 4);

    const long long nwaves = (long long)gridDim.x * 4;
    for (long long w = (long long)blockIdx.x * 4 + wib; w * 16 < E; w += nwaves) {
        const long long ebase = w * 16;
        float4 rv[4];
        #pragma unroll
        for (int u = 0; u < 4; ++u) {
            const long long e = ebase + u * 4 + group;
            rv[u] = (e < E) ? *reinterpret_cast<const float4*>(review_feat + e * 64 + sub * 4)
                            : make_float4(0.f, 0.f, 0.f, 0.f);
        }
        float x[4];
        #pragma unroll
        for (int u = 0; u < 4; ++u) {
            float t = rv[u].x * pw.x + rv[u].y * pw.y + rv[u].z * pw.z + rv[u].w * pw.w;
            t += __shfl_xor(t, 1);
            t += __shfl_xor(t, 2);
            t += __shfl_xor(t, 4);
            t += __shfl_xor(t, 8);
            x[u] = t;
        }
        if (sub == 0) {
            #pragma unroll
            for (int u = 0; u < 4; ++u) {
                const long long e = ebase + u * 4 + group;
                if (e < E) {
                    const int s_ = src[e];
                    const int d_ = dst[e];
                    const float g = 1.f / (1.f + __expf(-x[u]));
                    scale[e] = g * cj[s_] * ci[d_];   // fold cj*ci here
                    atomicAdd(&deg[d_], 1u);
                }
            }
        }
    }
}

// ---------------- K3: one-dispatch exclusive scan ----------------
// ntiles (=ceil(N/2048)=49) blocks, all co-resident on 256 CUs.
// Each block: coalesced tile scan in LDS -> publish aggregate (device atomic)
// -> barrier on done-counter -> serial prefix over <=48 aggregates ->
// coalesced offs/cursor writes.
__global__ __launch_bounds__(SCAN_THREADS) void k3_scan_onepass(
    const unsigned* __restrict__ deg,      // [N]
    unsigned*       __restrict__ offs,     // [N+1]
    unsigned*       __restrict__ cursor,   // [N]
    unsigned*       __restrict__ tileagg,  // [ntiles]
    unsigned*       __restrict__ done,     // [1] (pre-zeroed)
    int N, int ntiles)
{
    __shared__ unsigned lds[SCAN_TILE];
    __shared__ unsigned sums[SCAN_THREADS];
    __shared__ unsigned sh_prefix;
    const int t = threadIdx.x;
    const int b = blockIdx.x;
    const int base = b * SCAN_TILE;

    #pragma unroll
    for (int i = 0; i < SCAN_TILE / SCAN_THREADS; ++i) {
        const int idx = base + t + i * SCAN_THREADS;
        lds[t + i * SCAN_THREADS] = (idx < N) ? deg[idx] : 0u;   // coalesced
    }
    __syncthreads();

    unsigned v[SCAN_TILE / SCAN_THREADS];
    unsigned s = 0;
    #pragma unroll
    for (int i = 0; i < SCAN_TILE / SCAN_THREADS; ++i) {
        v[i] = lds[(SCAN_TILE / SCAN_THREADS) * t + i];
        s += v[i];
    }
    sums[t] = s;
    __syncthreads();
    for (int off = 1; off < SCAN_THREADS; off <<= 1) {   // Hillis-Steele
        const unsigned x = (t >= off) ? sums[t - off] : 0u;
        __syncthreads();
        sums[t] += x;
        __syncthreads();
    }
    unsigned run = sums[t] - s;   // exclusive prefix of this thread's chunk
    #pragma unroll
    for (int i = 0; i < SCAN_TILE / SCAN_THREADS; ++i) {
        lds[(SCAN_TILE / SCAN_THREADS) * t + i] = run;
        run += v[i];
    }
    __syncthreads();

    const unsigned agg = sums[SCAN_THREADS - 1];
    if (t == 0) {
        atomicExch(&tileagg[b], agg);     // publish (device scope)
        __threadfence();
        atomicAdd(done, 1u);
        while (atomicAdd(done, 0u) < (unsigned)ntiles) { }   // all published
        unsigned p = 0;
        for (int i = 0; i < b; ++i) p += atomicAdd(&tileagg[i], 0u);
        sh_prefix = p;
        if (b == ntiles - 1) offs[N] = p + agg;   // == E
    }
    __syncthreads();

    const unsigned pfx = sh_prefix;
    #pragma unroll
    for (int i = 0; i < SCAN_TILE / SCAN_THREADS; ++i) {
        const int idx = base + t + i * SCAN_THREADS;
        if (idx < N) {
            const unsigned o = lds[t + i * SCAN_THREADS] + pfx;
            offs[idx]   = o;
            cursor[idx] = o;
        }
    }
}

// ---------------- K4: CSR scatter, one thread per edge ----------------
__global__ __launch_bounds__(256) void k4_scatter(
    const int*   __restrict__ src,
    const int*   __restrict__ dst,
    const float* __restrict__ scale,
    unsigned*    __restrict__ cursor,
    int2*        __restrict__ pairs,
    int E)
{
    const long long e = (long long)blockIdx.x * 256 + threadIdx.x;
    if (e >= E) return;
    const int s = src[e];
    const int d = dst[e];
    const float sc = scale[e];                 // cj*ci already folded
    const unsigned pos = atomicAdd(&cursor[d], 1u);
    pairs[pos] = make_int2(s, __float_as_int(sc));
}

// ---------------- K5: gather-reduce (round-6 kD, unchanged) ----------------
__global__ __launch_bounds__(256, 4) void k5_gather(
    const float* __restrict__ weight, const unsigned* __restrict__ offs,
    const int2* __restrict__ pairs, float* __restrict__ out, int N)
{
    const int lane  = threadIdx.x & 63;
    const int wib   = threadIdx.x >> 6;
    const int group = lane >> 4;   // node within wave
    const int sub   = lane & 15;   // float4 chunk of the row

    const long long n = ((long long)blockIdx.x * 4 + wib) * 4 + group;
    const bool valid = (n < N);

    unsigned start = 0, cnt = 0;
    if (valid) { start = offs[n]; cnt = offs[n + 1] - start; }

    int2 p = make_int2(0, 0);
    if (sub < cnt) p = pairs[start + sub];

    float4 acc = make_float4(0.f, 0.f, 0.f, 0.f);
    for (unsigned k0 = 0; __any((int)(k0 < cnt)); k0 += 16) {
        int2 pn = make_int2(0, 0);
        const unsigned nk = k0 + 16;
        if (nk + sub < cnt) pn = pairs[start + nk + sub];

        int m = (int)cnt - (int)k0;
        if (m > 16) m = 16;
        #pragma unroll 8
        for (int j = 0; j < m; ++j) {
            const int   s  = __shfl(p.x, (group << 4) + j);
            const float sc = __int_as_float(__shfl(p.y, (group << 4) + j));
            const float4 w = *reinterpret_cast<const float4*>(
                weight + (long long)s * 64 + sub * 4);
            acc.x += sc * w.x;
            acc.y += sc * w.y;
            acc.z += sc * w.z;
            acc.w += sc * w.w;
        }
        p = pn;
    }
    if (valid)
        *reinterpret_cast<float4*>(out + n * 64 + sub * 4) = acc;
}

extern "C" void kernel_launch(void* const* d_in, const int* in_sizes, int n_in,
                              void* d_out, int out_size, void* d_ws, size_t ws_size,
                              hipStream_t stream) {
    const float* weight      = (const float*)d_in[0];
    const float* ps_w        = (const float*)d_in[1];
    const float* review_feat = (const float*)d_in[2];
    const float* cj          = (const float*)d_in[3];
    const float* ci          = (const float*)d_in[4];
    const int*   src         = (const int*)d_in[5];
    const int*   dst         = (const int*)d_in[6];
    float*       out         = (float*)d_out;

    const int N = in_sizes[3];
    const int E = in_sizes[5];
    const int ntiles = (N + SCAN_TILE - 1) / SCAN_TILE;

    size_t off = 0;
    auto take = [&](size_t bytes) { size_t o = off; off = (off + bytes + 255) & ~(size_t)255; return o; };
    const size_t pairs_o   = take((size_t)E * 8);
    const size_t scale_o   = take((size_t)E * 4);
    const size_t deg_o     = take((size_t)N * 4);
    const size_t offs_o    = take(((size_t)N + 1) * 4);
    const size_t cursor_o  = take((size_t)N * 4);
    const size_t tileagg_o = take((size_t)ntiles * 4);
    const size_t done_o    = take(4);

    char* base = (char*)d_ws;
    int2*     pairs   = (int2*)    (base + pairs_o);
    float*    scale   = (float*)   (base + scale_o);
    unsigned* deg     = (unsigned*)(base + deg_o);
    unsigned* offs    = (unsigned*)(base + offs_o);
    unsigned* cursor  = (unsigned*)(base + cursor_o);
    unsigned* tileagg = (unsigned*)(base + tileagg_o);
    unsigned* done    = (unsigned*)(base + done_o);

    kZ_zero<<<(N + 255) / 256, 256, 0, stream>>>(deg, done, N);
    k2_gate_hist<<<2048, 256, 0, stream>>>(review_feat, ps_w, cj, ci, src, dst,
                                           scale, deg, E);
    k3_scan_onepass<<<ntiles, SCAN_THREADS, 0, stream>>>(deg, offs, cursor,
                                                         tileagg, done, N, ntiles);
    k4_scatter<<<(E + 255) / 256, 256, 0, stream>>>(src, dst, scale, cursor, pairs, E);
    const int blocksD = (N + 15) / 16;   // 16 nodes per block (4 waves x 4 nodes)
    k5_gather<<<blocksD, 256, 0, stream>>>(weight, offs, pairs, out, N);
}

// Round 10
// 458.772 us; speedup vs baseline: 5.1986x; 1.2745x over previous
//
#include <hip/hip_runtime.h>

// out[n,:] = ci[n] * sum_{e: dst[e]==n} sigmoid(<review_feat[e,:], ps_w>) * cj[src[e]] * weight[src[e],:]
//
// Round-9 lesson (algebraic decomposition of rounds 6-8): the cursor-atomic
// scatter is ~240us -- not traffic, not atomic throughput, but the DEPENDENT
// CHAIN (pair write waits on the atomic's ~600cyc return; 1 edge/thread = no
// ILP). Round 10 makes the scatter PURE:
//   - k2's histogram atomicAdd already returns each edge's rank within its
//     dst bucket -> store rank[e] (rides under the 819MB stream).
//   - k4 becomes pairs[offs[dst[e]] + rank[e]] = (src, scale): no atomics,
//     no dependent chain, 4 edges/thread grid-stride for MLP.
// Pipeline: kZ zero | k2 gate+hist+rank | k3 one-pass scan | k4 pure scatter
//           | k5 gather (unchanged, at its L3 floor).

#define SCAN_TILE    2048
#define SCAN_THREADS 512

// ---------------- kZ: zero deg + done ----------------
__global__ __launch_bounds__(256) void kZ_zero(
    unsigned* __restrict__ deg, unsigned* __restrict__ done, int n)
{
    const int i = blockIdx.x * 256 + threadIdx.x;
    if (i < n) deg[i] = 0u;
    if (i == 0) *done = 0u;
}

// ---------------- K2: gate stream + hist/rank + cj*ci fold ----------------
__global__ __launch_bounds__(256) void k2_gate_hist(
    const float* __restrict__ review_feat,  // [E,64]
    const float* __restrict__ ps_w,         // [64]
    const float* __restrict__ cj,           // [N]
    const float* __restrict__ ci,           // [N]
    const int*   __restrict__ src,          // [E]
    const int*   __restrict__ dst,          // [E]
    float*       __restrict__ scale,        // [E] out: gate*cj*ci
    unsigned*    __restrict__ rank,         // [E] out: edge rank within dst bucket
    unsigned*    __restrict__ deg,          // [N] (pre-zeroed)
    int E)
{
    const int lane  = threadIdx.x & 63;
    const int wib   = threadIdx.x >> 6;
    const int group = lane >> 4;
    const int sub   = lane & 15;
    const float4 pw = *reinterpret_cast<const float4*>(ps_w + sub * 4);

    const long long nwaves = (long long)gridDim.x * 4;
    for (long long w = (long long)blockIdx.x * 4 + wib; w * 16 < E; w += nwaves) {
        const long long ebase = w * 16;
        float4 rv[4];
        #pragma unroll
        for (int u = 0; u < 4; ++u) {
            const long long e = ebase + u * 4 + group;
            rv[u] = (e < E) ? *reinterpret_cast<const float4*>(review_feat + e * 64 + sub * 4)
                            : make_float4(0.f, 0.f, 0.f, 0.f);
        }
        float x[4];
        #pragma unroll
        for (int u = 0; u < 4; ++u) {
            float t = rv[u].x * pw.x + rv[u].y * pw.y + rv[u].z * pw.z + rv[u].w * pw.w;
            t += __shfl_xor(t, 1);
            t += __shfl_xor(t, 2);
            t += __shfl_xor(t, 4);
            t += __shfl_xor(t, 8);
            x[u] = t;
        }
        if (sub == 0) {
            #pragma unroll
            for (int u = 0; u < 4; ++u) {
                const long long e = ebase + u * 4 + group;
                if (e < E) {
                    const int s_ = src[e];
                    const int d_ = dst[e];
                    const float g = 1.f / (1.f + __expf(-x[u]));
                    scale[e] = g * cj[s_] * ci[d_];          // fold cj*ci
                    rank[e]  = atomicAdd(&deg[d_], 1u);      // hist + rank in one op
                }
            }
        }
    }
}

// ---------------- K3: one-dispatch exclusive scan (offs only) ----------------
__global__ __launch_bounds__(SCAN_THREADS) void k3_scan_onepass(
    const unsigned* __restrict__ deg,      // [N]
    unsigned*       __restrict__ offs,     // [N+1]
    unsigned*       __restrict__ tileagg,  // [ntiles]
    unsigned*       __restrict__ done,     // [1] (pre-zeroed)
    int N, int ntiles)
{
    __shared__ unsigned lds[SCAN_TILE];
    __shared__ unsigned sums[SCAN_THREADS];
    __shared__ unsigned sh_prefix;
    const int t = threadIdx.x;
    const int b = blockIdx.x;
    const int base = b * SCAN_TILE;

    #pragma unroll
    for (int i = 0; i < SCAN_TILE / SCAN_THREADS; ++i) {
        const int idx = base + t + i * SCAN_THREADS;
        lds[t + i * SCAN_THREADS] = (idx < N) ? deg[idx] : 0u;   // coalesced
    }
    __syncthreads();

    unsigned v[SCAN_TILE / SCAN_THREADS];
    unsigned s = 0;
    #pragma unroll
    for (int i = 0; i < SCAN_TILE / SCAN_THREADS; ++i) {
        v[i] = lds[(SCAN_TILE / SCAN_THREADS) * t + i];
        s += v[i];
    }
    sums[t] = s;
    __syncthreads();
    for (int off = 1; off < SCAN_THREADS; off <<= 1) {   // Hillis-Steele
        const unsigned x = (t >= off) ? sums[t - off] : 0u;
        __syncthreads();
        sums[t] += x;
        __syncthreads();
    }
    unsigned run = sums[t] - s;
    #pragma unroll
    for (int i = 0; i < SCAN_TILE / SCAN_THREADS; ++i) {
        lds[(SCAN_TILE / SCAN_THREADS) * t + i] = run;
        run += v[i];
    }
    __syncthreads();

    const unsigned agg = sums[SCAN_THREADS - 1];
    if (t == 0) {
        atomicExch(&tileagg[b], agg);
        __threadfence();
        atomicAdd(done, 1u);
        while (atomicAdd(done, 0u) < (unsigned)ntiles) { }
        unsigned p = 0;
        for (int i = 0; i < b; ++i) p += atomicAdd(&tileagg[i], 0u);
        sh_prefix = p;
        if (b == ntiles - 1) offs[N] = p + agg;   // == E
    }
    __syncthreads();

    const unsigned pfx = sh_prefix;
    #pragma unroll
    for (int i = 0; i < SCAN_TILE / SCAN_THREADS; ++i) {
        const int idx = base + t + i * SCAN_THREADS;
        if (idx < N) offs[idx] = lds[t + i * SCAN_THREADS] + pfx;
    }
}

// ---------------- K4: PURE scatter (no atomics) ----------------
// pos = offs[dst[e]] + rank[e] is a precomputed permutation: every thread's
// work is independent; 4 edges/thread grid-stride for memory-level parallelism.
__global__ __launch_bounds__(256) void k4_scatter_pure(
    const int*      __restrict__ src,
    const int*      __restrict__ dst,
    const float*    __restrict__ scale,
    const unsigned* __restrict__ rank,
    const unsigned* __restrict__ offs,
    int2*           __restrict__ pairs,
    int E)
{
    const long long stride = (long long)gridDim.x * blockDim.x;
    long long e = (long long)blockIdx.x * blockDim.x + threadIdx.x;
    #pragma unroll 4
    for (int u = 0; u < 4; ++u, e += stride) {
        if (e < E) {
            const int s = src[e];
            const int d = dst[e];
            const unsigned pos = offs[d] + rank[e];
            pairs[pos] = make_int2(s, __float_as_int(scale[e]));
        }
    }
}

// ---------------- K5: gather-reduce (unchanged; at its L3-BW floor) ----------------
__global__ __launch_bounds__(256, 4) void k5_gather(
    const float* __restrict__ weight, const unsigned* __restrict__ offs,
    const int2* __restrict__ pairs, float* __restrict__ out, int N)
{
    const int lane  = threadIdx.x & 63;
    const int wib   = threadIdx.x >> 6;
    const int group = lane >> 4;   // node within wave
    const int sub   = lane & 15;   // float4 chunk of the row

    const long long n = ((long long)blockIdx.x * 4 + wib) * 4 + group;
    const bool valid = (n < N);

    unsigned start = 0, cnt = 0;
    if (valid) { start = offs[n]; cnt = offs[n + 1] - start; }

    int2 p = make_int2(0, 0);
    if (sub < cnt) p = pairs[start + sub];

    float4 acc = make_float4(0.f, 0.f, 0.f, 0.f);
    for (unsigned k0 = 0; __any((int)(k0 < cnt)); k0 += 16) {
        int2 pn = make_int2(0, 0);
        const unsigned nk = k0 + 16;
        if (nk + sub < cnt) pn = pairs[start + nk + sub];

        int m = (int)cnt - (int)k0;
        if (m > 16) m = 16;
        #pragma unroll 8
        for (int j = 0; j < m; ++j) {
            const int   s  = __shfl(p.x, (group << 4) + j);
            const float sc = __int_as_float(__shfl(p.y, (group << 4) + j));
            const float4 w = *reinterpret_cast<const float4*>(
                weight + (long long)s * 64 + sub * 4);
            acc.x += sc * w.x;
            acc.y += sc * w.y;
            acc.z += sc * w.z;
            acc.w += sc * w.w;
        }
        p = pn;
    }
    if (valid)
        *reinterpret_cast<float4*>(out + n * 64 + sub * 4) = acc;
}

extern "C" void kernel_launch(void* const* d_in, const int* in_sizes, int n_in,
                              void* d_out, int out_size, void* d_ws, size_t ws_size,
                              hipStream_t stream) {
    const float* weight      = (const float*)d_in[0];
    const float* ps_w        = (const float*)d_in[1];
    const float* review_feat = (const float*)d_in[2];
    const float* cj          = (const float*)d_in[3];
    const float* ci          = (const float*)d_in[4];
    const int*   src         = (const int*)d_in[5];
    const int*   dst         = (const int*)d_in[6];
    float*       out         = (float*)d_out;

    const int N = in_sizes[3];
    const int E = in_sizes[5];
    const int ntiles = (N + SCAN_TILE - 1) / SCAN_TILE;

    size_t off = 0;
    auto take = [&](size_t bytes) { size_t o = off; off = (off + bytes + 255) & ~(size_t)255; return o; };
    const size_t pairs_o   = take((size_t)E * 8);
    const size_t scale_o   = take((size_t)E * 4);
    const size_t rank_o    = take((size_t)E * 4);
    const size_t deg_o     = take((size_t)N * 4);
    const size_t offs_o    = take(((size_t)N + 1) * 4);
    const size_t tileagg_o = take((size_t)ntiles * 4);
    const size_t done_o    = take(4);

    char* base = (char*)d_ws;
    int2*     pairs   = (int2*)    (base + pairs_o);
    float*    scale   = (float*)   (base + scale_o);
    unsigned* rank    = (unsigned*)(base + rank_o);
    unsigned* deg     = (unsigned*)(base + deg_o);
    unsigned* offs    = (unsigned*)(base + offs_o);
    unsigned* tileagg = (unsigned*)(base + tileagg_o);
    unsigned* done    = (unsigned*)(base + done_o);

    kZ_zero<<<(N + 255) / 256, 256, 0, stream>>>(deg, done, N);
    k2_gate_hist<<<2048, 256, 0, stream>>>(review_feat, ps_w, cj, ci, src, dst,
                                           scale, rank, deg, E);
    k3_scan_onepass<<<ntiles, SCAN_THREADS, 0, stream>>>(deg, offs, tileagg, done,
                                                         N, ntiles);
    const int blocks4 = (int)(((long long)E + 4LL * 256 - 1) / (4LL * 256));
    k4_scatter_pure<<<blocks4, 256, 0, stream>>>(src, dst, scale, rank, offs, pairs, E);
    const int blocksD = (N + 15) / 16;   // 16 nodes per block (4 waves x 4 nodes)
    k5_gather<<<blocksD, 256, 0, stream>>>(weight, offs, pairs, out, N);
}